// Round 3
// baseline (854.000 us; speedup 1.0000x reference)
//
#include <hip/hip_runtime.h>

#define HD 256
#define NCH 64
#define NB 16
#define NPC (NB * HD * HD)          // BN population per channel = 1048576
#define PLANE (HD * HD)             // 65536

typedef __attribute__((ext_vector_type(4))) float f32x4;
typedef __attribute__((ext_vector_type(8))) short s16x8;

__device__ __forceinline__ short f2bf(float f) {
    unsigned u = __float_as_uint(f);
    u += 0x7FFFu + ((u >> 16) & 1u);   // round-to-nearest-even
    return (short)(u >> 16);
}

// One block per (batch, channel) plane. 512 threads = 8 waves.
// LDS: 64 KB = 256 rows x 16 chunks x 8 bf16, chunk column XOR-swizzled by (row&15)
// so ds_read_b128 fragment reads are conflict-free (2-way max = free).
// K=256 processed in 2 phases of BK=128. Frag grid 16x16; only fk>=fi computed (136 frags).
// Wave (waveM=wid>>2, waveN=wid&3): fi = waveM*8+mi (mi 0..7), fk = waveN*4+ni (ni 0..3).
// Waves 4,5 (waveM=1, waveN<2) have zero live frags -> in PASS1 they fill the constant
// lower-left 128x128 region during the compute slot.
// PASS 0: stats only (sum, sumsq via block reduce + atomics into ws).
// PASS 1: recompute, normalize, store.
template <int PASS>
__global__ __launch_bounds__(512) void gram_bn(
    const float* __restrict__ x, const float* __restrict__ w,
    const float* __restrict__ gamma, const float* __restrict__ beta,
    float* __restrict__ out, float* __restrict__ stats)
{
    const int b   = blockIdx.x;
    const int c   = blockIdx.y;
    const int n   = b * NCH + c;
    const int tid = threadIdx.x;
    const int wid   = tid >> 6;
    const int lane  = tid & 63;
    const int waveM = wid >> 2;      // 0..1
    const int waveN = wid & 3;       // 0..3
    const int lrow  = lane & 15;
    const int q     = lane >> 4;     // 0..3

    __shared__ short As[32768];      // 64 KB staging buffer (aliased as red[] in PASS0)

    float scale = 0.f, shift = 0.f;
    if (PASS == 1) {
        float s    = stats[2 * c];
        float sq   = stats[2 * c + 1];
        float mean = s * (1.0f / (float)NPC);
        float var  = sq * (1.0f / (float)NPC) - mean * mean;
        float rstd = rsqrtf(var + 1e-5f);
        scale = rstd * gamma[c];
        shift = beta[c] - mean * scale;
    }

    const float* xp = x + (size_t)n * PLANE;

    f32x4 acc[8][4];
#pragma unroll
    for (int i = 0; i < 8; ++i)
#pragma unroll
        for (int j = 0; j < 4; ++j)
            acc[i][j] = (f32x4){0.f, 0.f, 0.f, 0.f};

    for (int kb = 0; kb < 2; ++kb) {
        // ---- stage 256 rows x 128 k: fp32 -> bf16 -> swizzled LDS ----
#pragma unroll
        for (int it = 0; it < 8; ++it) {
            int g2  = it * 512 + tid;          // bf16-chunk id, 0..4095
            int row = g2 >> 4;
            int c8  = g2 & 15;
            const float* src = xp + (size_t)row * HD + kb * 128 + c8 * 8;
            f32x4 a0 = *(const f32x4*)src;
            f32x4 a1 = *(const f32x4*)(src + 4);
            s16x8 o = { f2bf(a0.x), f2bf(a0.y), f2bf(a0.z), f2bf(a0.w),
                        f2bf(a1.x), f2bf(a1.y), f2bf(a1.z), f2bf(a1.w) };
            *(s16x8*)&As[(row * 16 + (c8 ^ (row & 15))) * 8] = o;
        }
        __syncthreads();

        if (PASS == 1 && kb == 0 && (wid == 4 || wid == 5)) {
            // all-masked lower-left quadrant -> constant after BN; do it in the idle slot
            f32x4 cv = {shift, shift, shift, shift};
            float* op = out + (size_t)n * PLANE;
#pragma unroll
            for (int it = 0; it < 32; ++it) {
                int idx = it * 128 + (wid - 4) * 64 + lane;   // 0..4095
                int row = 128 + (idx >> 5);
                int c4  = idx & 31;
                *(f32x4*)&op[(size_t)row * HD + c4 * 4] = cv;
            }
        }

        // ---- compute: 4 k-steps of 32 over this BK=128 phase ----
#pragma unroll
        for (int kk = 0; kk < 4; ++kk) {
            s16x8 af[8], bf_[4];
#pragma unroll
            for (int ni = 0; ni < 4; ++ni) {
                int fk  = waveN * 4 + ni;
                int row = fk * 16 + lrow;
                bf_[ni] = *(s16x8*)&As[(row * 16 + ((kk * 4 + q) ^ lrow)) * 8];
            }
#pragma unroll
            for (int mi = 0; mi < 8; ++mi) {
                int fi = waveM * 8 + mi;
                if (waveN * 4 + 3 >= fi) {         // at least one live ni
                    int row = fi * 16 + lrow;
                    af[mi] = *(s16x8*)&As[(row * 16 + ((kk * 4 + q) ^ lrow)) * 8];
                }
            }
#pragma unroll
            for (int mi = 0; mi < 8; ++mi) {
                int fi = waveM * 8 + mi;
#pragma unroll
                for (int ni = 0; ni < 4; ++ni) {
                    int fk = waveN * 4 + ni;
                    if (fk >= fi)
                        acc[mi][ni] = __builtin_amdgcn_mfma_f32_16x16x32_bf16(
                            af[mi], bf_[ni], acc[mi][ni], 0, 0, 0);
                }
            }
        }
        __syncthreads();   // protect LDS (WAR for next phase / reuse for reduction)
    }

    // ---- epilogue: mask, weight, stats or normalized store ----
    float lsum = 0.f, lsq = 0.f;
    const float* wp = w + (size_t)c * PLANE;
    float* op = out + (size_t)n * PLANE;
    const int row0 = q * 4;          // C/D: row = (lane>>4)*4 + reg, col = lane&15
#pragma unroll
    for (int mi = 0; mi < 8; ++mi) {
        int fi = waveM * 8 + mi;
#pragma unroll
        for (int ni = 0; ni < 4; ++ni) {
            int fk = waveN * 4 + ni;
            if (fk >= fi) {
                int gk = fk * 16 + lrow;
#pragma unroll
                for (int r = 0; r < 4; ++r) {
                    int gi = fi * 16 + row0 + r;
                    float v   = acc[mi][ni][r];
                    float val = (gk >= gi) ? v * wp[(size_t)gi * HD + gk] : 0.f;
                    if (PASS == 0) {
                        lsum += val;
                        lsq  += val * val;
                    } else {
                        op[(size_t)gi * HD + gk] = val * scale + shift;
                    }
                }
            }
        }
    }

    if (PASS == 0) {
        float* red = (float*)As;     // LDS reuse (all reads done, post-barrier)
        red[tid]        = lsum;
        red[512 + tid]  = lsq;
        __syncthreads();
        for (int s = 256; s > 0; s >>= 1) {
            if (tid < s) {
                red[tid]       += red[tid + s];
                red[512 + tid] += red[512 + tid + s];
            }
            __syncthreads();
        }
        if (tid == 0) {
            atomicAdd(&stats[2 * c],     red[0]);
            atomicAdd(&stats[2 * c + 1], red[512]);
        }
    }
}

extern "C" void kernel_launch(void* const* d_in, const int* in_sizes, int n_in,
                              void* d_out, int out_size, void* d_ws, size_t ws_size,
                              hipStream_t stream) {
    const float* x     = (const float*)d_in[0];
    const float* w     = (const float*)d_in[1];
    const float* gamma = (const float*)d_in[2];
    const float* beta  = (const float*)d_in[3];
    float* out   = (float*)d_out;
    float* stats = (float*)d_ws;

    hipMemsetAsync(d_ws, 0, 128 * sizeof(float), stream);

    gram_bn<0><<<dim3(NB, NCH), dim3(512), 0, stream>>>(x, w, gamma, beta, out, stats);
    gram_bn<1><<<dim3(NB, NCH), dim3(512), 0, stream>>>(x, w, gamma, beta, out, stats);
}